// Round 7
// baseline (76.029 us; speedup 1.0000x reference)
//
#include <hip/hip_runtime.h>

#define H 512
#define W 512
#define NIMG 8
#define SW 513                    // SAT logical dimension (H+1)
#define SAT_PER (SW * SW)
#define NBAND 32
#define BROWS 16                  // rows per band (NBAND*BROWS == H)

#define PS 576                    // padded SAT stride (32 + 513 + 31)
#define PP (PS * PS)              // padded plane size
#define PADY 32
#define PADX 32

typedef float f4 __attribute__((ext_vector_type(4), aligned(4)));

// dword-aligned float4 load -> global_load_dwordx4 (HW tolerates 4B alignment)
__device__ __forceinline__ f4 ld4(const float* p) {
    return *reinterpret_cast<const f4*>(p);
}

// zero-padded global load ('SAME' conv padding)
__device__ __forceinline__ float ldz(const float* __restrict__ p, int y, int x) {
    return ((unsigned)y < (unsigned)H && (unsigned)x < (unsigned)W) ? p[y * W + x] : 0.0f;
}

// ---- kernel 1: energy + row prefix + band-local column prefix ------------
// One block = one 16-row band of one (image, map).
__global__ __launch_bounds__(512) void k_rowband(const float* __restrict__ v,
                                                 const float* __restrict__ i_,
                                                 float* __restrict__ B) {
    const int band = blockIdx.x;
    const int n = blockIdx.y;
    const int m = blockIdx.z;
    const float* src = (m == 0 ? v : i_) + (size_t)n * (H * W);
    float* Bm = B + (size_t)(n * 2 + m) * SAT_PER;

    __shared__ float tile[BROWS][SW];          // 16*513*4 = 32.8 KB

    const int lane = threadIdx.x & 63;
    const int wv   = threadIdx.x >> 6;         // 0..7
    const int x0   = lane * 8;

    #pragma unroll
    for (int k = 0; k < 2; ++k) {
        const int j = k * 8 + wv;              // row within band
        const int y = band * BROWS + j;
        float a[10], b[10], c[10];
        #pragma unroll
        for (int q = 0; q < 10; ++q) {
            int xx = x0 - 1 + q;
            a[q] = ldz(src, y - 1, xx);
            b[q] = ldz(src, y,     xx);
            c[q] = ldz(src, y + 1, xx);
        }
        float e[8];
        #pragma unroll
        for (int q = 0; q < 8; ++q) {
            float gx = (a[q + 2] - a[q]) + 2.0f * (b[q + 2] - b[q]) + (c[q + 2] - c[q]);
            float gy = (c[q] - a[q]) + 2.0f * (c[q + 1] - a[q + 1]) + (c[q + 2] - a[q + 2]);
            e[q] = gx * gx + gy * gy;
        }
        #pragma unroll
        for (int q = 1; q < 8; ++q) e[q] += e[q - 1];   // in-lane prefix
        const float tot = e[7];
        float s = tot;                                   // wave scan of totals
        #pragma unroll
        for (int off = 1; off < 64; off <<= 1) {
            float t = __shfl_up(s, off, 64);
            if (lane >= off) s += t;
        }
        const float excl = s - tot;
        if (lane == 0) tile[j][0] = 0.0f;
        #pragma unroll
        for (int q = 0; q < 8; ++q) tile[j][1 + x0 + q] = e[q] + excl;
    }
    __syncthreads();

    // band-local column prefix (inclusive) over the 16 rows
    for (int c2 = threadIdx.x; c2 < SW; c2 += 512) {
        float run = 0.0f;
        #pragma unroll
        for (int j = 0; j < BROWS; ++j) {
            run += tile[j][c2];
            tile[j][c2] = run;
        }
    }
    __syncthreads();

    #pragma unroll
    for (int j = 0; j < BROWS; ++j)
        for (int c2 = threadIdx.x; c2 < SW; c2 += 512)
            Bm[(size_t)(1 + band * BROWS + j) * SW + c2] = tile[j][c2];
}

// ---- kernel 2: exclusive scan of band boundary rows -> C ------------------
// C[map][b][c] = sum over b'<b of B[map][BROWS*(b'+1)][c]
__global__ __launch_bounds__(256) void k_bandscan(const float* __restrict__ B,
                                                  float* __restrict__ C) {
    const int c = blockIdx.x * 256 + threadIdx.x;
    if (c >= SW) return;
    const int map = blockIdx.y;
    const float* Bm = B + (size_t)map * SAT_PER;
    float* Cm = C + (size_t)map * NBAND * SW;
    float run = 0.0f;
    #pragma unroll
    for (int b = 0; b < NBAND; ++b) {
        Cm[(size_t)b * SW + c] = run;
        run += Bm[(size_t)((b + 1) * BROWS) * SW + c];
    }
}

// ---- kernel 3: finalize padded SAT P = B + C (clamp-free padding) --------
// 8 rows per block.
__global__ __launch_bounds__(256) void k_finalize(const float* __restrict__ B,
                                                  const float* __restrict__ C,
                                                  float* __restrict__ P) {
    const int p0 = blockIdx.x * 8;
    const int mp = blockIdx.y;       // 0..15
    #pragma unroll
    for (int r = 0; r < 8; ++r) {
        const int p = p0 + r;
        float* dst = P + (size_t)mp * PP + (size_t)p * PS;
        const int ys = p - PADY;
        if (ys <= 0) {
            for (int c = threadIdx.x; c < PS; c += 256) dst[c] = 0.0f;
        } else {
            const int y = min(ys, H);
            const int b = (y - 1) >> 4;            // BROWS = 16
            const float* Brow = B + (size_t)mp * SAT_PER + (size_t)y * SW;
            const float* Crow = C + ((size_t)mp * NBAND + b) * SW;
            for (int c = threadIdx.x; c < PS; c += 256) {
                int x = min(max(c - PADX, 0), W);
                dst[c] = Brow[x] + Crow[x];
            }
        }
    }
}

// ---- sobel for 4 consecutive pixels --------------------------------------
__device__ __forceinline__ void sobel4(const float* __restrict__ p, int y, int x4,
                                       bool fast, float gx[4], float gy[4]) {
    float r0[6], r1[6], r2[6];
    if (fast) {
        const float* a = p + (size_t)(y - 1) * W + (x4 - 1);
        #pragma unroll
        for (int q = 0; q < 6; ++q) {
            r0[q] = a[q]; r1[q] = a[W + q]; r2[q] = a[2 * W + q];
        }
    } else {
        #pragma unroll
        for (int q = 0; q < 6; ++q) {
            r0[q] = ldz(p, y - 1, x4 - 1 + q);
            r1[q] = ldz(p, y,     x4 - 1 + q);
            r2[q] = ldz(p, y + 1, x4 - 1 + q);
        }
    }
    #pragma unroll
    for (int q = 0; q < 4; ++q) {
        gx[q] = (r0[q + 2] - r0[q]) + 2.0f * (r1[q + 2] - r1[q]) + (r2[q + 2] - r2[q]);
        gy[q] = (r2[q] - r0[q]) + 2.0f * (r2[q + 1] - r0[q + 1]) + (r2[q + 2] - r0[q + 2]);
    }
}

// ---- kernel 4: fused sobel + clamp-free f4 SAT gather + residual ---------
__global__ __launch_bounds__(256) void k_main(const float* __restrict__ v,
                                              const float* __restrict__ i_,
                                              const float* __restrict__ img,
                                              const float* __restrict__ P,
                                              double* __restrict__ partials) {
    const int bid = blockIdx.x;
    const int n = bid & 7;                     // image -> XCD round-robin
    const int t = bid >> 3;                    // 0..255
    const int tx = t & 3, ty = t >> 2;         // tile: 128 wide x 8 rows
    const int col = threadIdx.x & 31, row = threadIdx.x >> 5;
    const int x4 = tx * 128 + col * 4;
    const int y  = ty * 8 + row;

    const float* pv = v   + (size_t)n * (H * W);
    const float* pi = i_  + (size_t)n * (H * W);
    const float* pf = img + (size_t)n * (H * W);
    const float* Pv = P + (size_t)(n * 2 + 0) * PP;
    const float* Pi = P + (size_t)(n * 2 + 1) * PP;

    float gvx[4], gvy[4], gix[4], giy[4], gfx[4], gfy[4];
    const bool fast = (y >= 1 && y <= H - 2 && x4 >= 4 && x4 <= W - 8);
    sobel4(pv, y, x4, fast, gvx, gvy);
    sobel4(pi, y, x4, fast, gix, giy);
    sobel4(pf, y, x4, fast, gfx, gfy);

    const int   radii[5] = {1, 3, 7, 15, 30};
    const float iw2[5]   = {1.0f / 9.0f, 1.0f / 49.0f, 1.0f / 225.0f,
                            1.0f / 961.0f, 1.0f / 3721.0f};

    float acc = 0.0f;
    #pragma unroll
    for (int k = 0; k < 5; ++k) {
        const int r = radii[k];
        const size_t ro0 = (size_t)(y - r + PADY) * PS;
        const size_t ro1 = (size_t)(y + r + 1 + PADY) * PS;
        const int x0 = x4 - r + PADX;
        const int x1 = x4 + r + 1 + PADX;
        f4 sa = ld4(Pv + ro1 + x1), sb = ld4(Pv + ro0 + x1);
        f4 sc = ld4(Pv + ro1 + x0), sd = ld4(Pv + ro0 + x0);
        f4 ua = ld4(Pi + ro1 + x1), ub = ld4(Pi + ro0 + x1);
        f4 uc = ld4(Pi + ro1 + x0), ud = ld4(Pi + ro0 + x0);
        f4 sv = sa - sb - sc + sd;
        f4 si = ua - ub - uc + ud;
        #pragma unroll
        for (int q = 0; q < 4; ++q) {
            float ev = sv[q] * iw2[k];
            float ei = si[q] * iw2[k];
            float wt = ev / (ev + ei + 1e-8f);
            float txv = gix[q] + wt * (gvx[q] - gix[q]);
            float tyv = giy[q] + wt * (gvy[q] - giy[q]);
            float dx = gfx[q] - txv, dy = gfy[q] - tyv;
            acc += dx * dx + dy * dy;
        }
    }

    // block reduction (f64, deterministic)
    double a = (double)acc;
    const int lane = threadIdx.x & 63, wid = threadIdx.x >> 6;
    #pragma unroll
    for (int off = 32; off > 0; off >>= 1) a += __shfl_down(a, off, 64);
    __shared__ double red[4];
    if (lane == 0) red[wid] = a;
    __syncthreads();
    if (threadIdx.x == 0)
        partials[bid] = red[0] + red[1] + red[2] + red[3];
}

// ---- kernel 5: final reduce ----------------------------------------------
__global__ __launch_bounds__(256) void k_reduce(const double* __restrict__ partials,
                                                int np, float* __restrict__ out) {
    __shared__ double red[256];
    double s = 0.0;
    for (int idx = threadIdx.x; idx < np; idx += 256) s += partials[idx];
    red[threadIdx.x] = s;
    __syncthreads();
    #pragma unroll
    for (int t = 128; t > 0; t >>= 1) {
        if (threadIdx.x < t) red[threadIdx.x] += red[threadIdx.x + t];
        __syncthreads();
    }
    if (threadIdx.x == 0)
        out[0] = (float)(red[0] / (double)((size_t)NIMG * H * W));
}

// ---- launch --------------------------------------------------------------

extern "C" void kernel_launch(void* const* d_in, const int* in_sizes, int n_in,
                              void* d_out, int out_size, void* d_ws, size_t ws_size,
                              hipStream_t stream) {
    const float* v   = (const float*)d_in[0];
    const float* i_  = (const float*)d_in[1];
    const float* img = (const float*)d_in[2];
    float* out = (float*)d_out;

    float* B         = (float*)d_ws;                               // 16 * 513*513 f32 = 16.8 MB
    float* C         = B + (size_t)16 * SAT_PER;                   // 16 * 32 * 513 f32
    float* P         = C + (size_t)16 * NBAND * SW;                // 16 * 576*576 f32 = 21.2 MB
    double* partials = (double*)(P + (size_t)16 * PP);             // 2048 f64

    k_rowband<<<dim3(NBAND, NIMG, 2), dim3(512), 0, stream>>>(v, i_, B);
    k_bandscan<<<dim3(3, 16), dim3(256), 0, stream>>>(B, C);
    k_finalize<<<dim3(PS / 8, 16), dim3(256), 0, stream>>>(B, C, P);
    k_main<<<dim3(2048), dim3(256), 0, stream>>>(v, i_, img, P, partials);
    k_reduce<<<dim3(1), dim3(256), 0, stream>>>(partials, 2048, out);
}

// Round 8
// 56.849 us; speedup vs baseline: 1.3374x; 1.3374x over previous
//
#include <hip/hip_runtime.h>

#define H 512
#define W 512
#define NIMG 8
#define SW 513                    // SAT logical dimension (H+1)
#define SAT_PER (SW * SW)
#define NBAND 16
#define BROWS 32                  // rows per band (NBAND*BROWS == H)

#define PS 576                    // padded SAT stride
#define PP (PS * PS)
#define PADY 32
#define PADX 32

typedef float f4 __attribute__((ext_vector_type(4), aligned(4)));

// dword-aligned float4 load (gfx9 global loads need only 4B alignment)
__device__ __forceinline__ f4 ld4(const float* p) {
    return *reinterpret_cast<const f4*>(p);
}

// zero-padded global load ('SAME' conv padding)
__device__ __forceinline__ float ldz(const float* __restrict__ p, int y, int x) {
    return ((unsigned)y < (unsigned)H && (unsigned)x < (unsigned)W) ? p[y * W + x] : 0.0f;
}

// ---- kernel 1: Sobel energy + row-inclusive prefix (f32, shuffle scan) ---
// 1-D grid: n = bid&7 (XCD pin), m = (bid>>3)&1, y = bid>>4.
__global__ __launch_bounds__(512) void k_rowscan(const float* __restrict__ v,
                                                 const float* __restrict__ i_,
                                                 float* __restrict__ B) {
    const int bid = blockIdx.x;
    const int n = bid & 7;
    const int t = bid >> 3;
    const int m = t & 1;
    const int y = t >> 1;
    const int x = threadIdx.x;   // 0..511
    const float* src = (m == 0 ? v : i_) + (size_t)n * (H * W);

    float gx, gy;
    {
        float a00 = ldz(src, y - 1, x - 1), a01 = ldz(src, y - 1, x), a02 = ldz(src, y - 1, x + 1);
        float a10 = ldz(src, y,     x - 1),                            a12 = ldz(src, y,     x + 1);
        float a20 = ldz(src, y + 1, x - 1), a21 = ldz(src, y + 1, x), a22 = ldz(src, y + 1, x + 1);
        gx = (a02 - a00) + 2.0f * (a12 - a10) + (a22 - a20);
        gy = (a20 - a00) + 2.0f * (a21 - a01) + (a22 - a02);
    }
    float e = gx * gx + gy * gy;

    const int lane = x & 63, wid = x >> 6;
    float s = e;
    #pragma unroll
    for (int off = 1; off < 64; off <<= 1) {
        float t2 = __shfl_up(s, off, 64);
        if (lane >= off) s += t2;
    }
    __shared__ float wt[8];
    if (lane == 63) wt[wid] = s;
    __syncthreads();
    float o = 0.0f;
    for (int w2 = 0; w2 < wid; ++w2) o += wt[w2];   // uniform within wave
    float incl = s + o;

    float* row = B + (size_t)(n * 2 + m) * SAT_PER + (size_t)(y + 1) * SW;
    row[x + 1] = incl;
    if (x == 0) row[0] = 0.0f;
}

// ---- kernel 2: per-band column sums --------------------------------------
// 1-D grid 256: n = bid&7, m = (bid>>3)&1, b = bid>>4. 576 thr, c<513.
__global__ __launch_bounds__(576) void k_bandsum(const float* __restrict__ B,
                                                 float* __restrict__ bandsum) {
    const int bid = blockIdx.x;
    const int n = bid & 7;
    const int t = bid >> 3;
    const int m = t & 1;
    const int b = t >> 1;
    const int c = threadIdx.x;
    if (c >= SW) return;
    const int map = n * 2 + m;
    const float* base = B + (size_t)map * SAT_PER + (size_t)(1 + b * BROWS) * SW + c;
    float s = 0.0f;
    #pragma unroll 8
    for (int r = 0; r < BROWS; ++r) s += base[(size_t)r * SW];
    bandsum[((size_t)map * NBAND + b) * SW + c] = s;
}

// ---- kernel 3: band apply -> padded final SAT P (inline band scan) -------
// P[p][c]: p = SAT y + 32; rows p<=32 zero; p>=545 replicate SAT row 512;
// cols c<=32 are SAT col 0 (zero); c>=545 replicate SAT col 512.
__global__ __launch_bounds__(576) void k_bandapplyP(const float* __restrict__ B,
                                                    const float* __restrict__ bandsum,
                                                    float* __restrict__ P) {
    const int bid = blockIdx.x;
    const int n = bid & 7;
    const int t = bid >> 3;
    const int m = t & 1;
    const int b = t >> 1;
    const int c = threadIdx.x;          // 0..575 (one P column)
    const int map = n * 2 + m;
    const int x = min(max(c - PADX, 0), W);

    float* Pm = P + (size_t)map * PP;
    const float* Bm = B + (size_t)map * SAT_PER;
    const float* bs = bandsum + (size_t)map * NBAND * SW + x;

    if (b == 0) {                       // top pad + SAT row 0: rows 0..32 = 0
        #pragma unroll
        for (int j = 0; j <= PADY; ++j)
            Pm[(size_t)j * PS + c] = 0.0f;
    }

    float run = 0.0f;
    for (int bb = 0; bb < b; ++bb) run += bs[(size_t)bb * SW];

    const float* Brow = Bm + (size_t)(1 + b * BROWS) * SW + x;
    float* Prow = Pm + (size_t)(PADY + 1 + b * BROWS) * PS + c;
    #pragma unroll 8
    for (int j = 0; j < BROWS; ++j) {
        run += Brow[(size_t)j * SW];
        Prow[(size_t)j * PS] = run;
    }

    if (b == NBAND - 1) {               // bottom pad: rows 545..575 = SAT row 512
        float* Ppad = Pm + (size_t)(PADY + 1 + H) * PS + c;
        #pragma unroll
        for (int j = 0; j < PS - (PADY + 1 + H); ++j)
            Ppad[(size_t)j * PS] = run;
    }
}

// ---- sobel for 4 consecutive pixels --------------------------------------
__device__ __forceinline__ void sobel4(const float* __restrict__ p, int y, int x4,
                                       bool fast, float gx[4], float gy[4]) {
    float r0[6], r1[6], r2[6];
    if (fast) {
        const float* a = p + (size_t)(y - 1) * W + (x4 - 1);
        #pragma unroll
        for (int q = 0; q < 6; ++q) {
            r0[q] = a[q]; r1[q] = a[W + q]; r2[q] = a[2 * W + q];
        }
    } else {
        #pragma unroll
        for (int q = 0; q < 6; ++q) {
            r0[q] = ldz(p, y - 1, x4 - 1 + q);
            r1[q] = ldz(p, y,     x4 - 1 + q);
            r2[q] = ldz(p, y + 1, x4 - 1 + q);
        }
    }
    #pragma unroll
    for (int q = 0; q < 4; ++q) {
        gx[q] = (r0[q + 2] - r0[q]) + 2.0f * (r1[q + 2] - r1[q]) + (r2[q + 2] - r2[q]);
        gy[q] = (r2[q] - r0[q]) + 2.0f * (r2[q + 1] - r0[q + 1]) + (r2[q + 2] - r0[q + 2]);
    }
}

// ---- kernel 4: fused sobel + clamp-free f4 SAT gather + residual ---------
__global__ __launch_bounds__(256) void k_main(const float* __restrict__ v,
                                              const float* __restrict__ i_,
                                              const float* __restrict__ img,
                                              const float* __restrict__ P,
                                              double* __restrict__ partials) {
    const int bid = blockIdx.x;
    const int n = bid & 7;                     // image -> XCD pin
    const int t = bid >> 3;                    // 0..255
    const int tx = t & 3, ty = t >> 2;         // tile: 128 wide x 8 rows
    const int col = threadIdx.x & 31, row = threadIdx.x >> 5;
    const int x4 = tx * 128 + col * 4;
    const int y  = ty * 8 + row;

    const float* pv = v   + (size_t)n * (H * W);
    const float* pi = i_  + (size_t)n * (H * W);
    const float* pf = img + (size_t)n * (H * W);
    const float* Pv = P + (size_t)(n * 2 + 0) * PP;
    const float* Pi = P + (size_t)(n * 2 + 1) * PP;

    float gvx[4], gvy[4], gix[4], giy[4], gfx[4], gfy[4];
    const bool fast = (y >= 1 && y <= H - 2 && x4 >= 4 && x4 <= W - 8);
    sobel4(pv, y, x4, fast, gvx, gvy);
    sobel4(pi, y, x4, fast, gix, giy);
    sobel4(pf, y, x4, fast, gfx, gfy);

    float dvx[4], dvy[4], rx[4], ry[4];
    #pragma unroll
    for (int q = 0; q < 4; ++q) {
        dvx[q] = gvx[q] - gix[q];
        dvy[q] = gvy[q] - giy[q];
        rx[q]  = gfx[q] - gix[q];
        ry[q]  = gfy[q] - giy[q];
    }

    const int   radii[5] = {1, 3, 7, 15, 30};
    // eps * w^2 (wt = sv / (sv + si + eps*w^2), identical algebra to ref)
    const float epsw[5]  = {9e-8f, 4.9e-7f, 2.25e-6f, 9.61e-6f, 3.721e-5f};

    float acc = 0.0f;
    #pragma unroll
    for (int k = 0; k < 5; ++k) {
        const int r = radii[k];
        const size_t ro0 = (size_t)(y - r + PADY) * PS;
        const size_t ro1 = (size_t)(y + r + 1 + PADY) * PS;
        const int x0 = x4 - r + PADX;
        const int x1 = x4 + r + 1 + PADX;
        f4 sa = ld4(Pv + ro1 + x1), sb = ld4(Pv + ro0 + x1);
        f4 sc = ld4(Pv + ro1 + x0), sd = ld4(Pv + ro0 + x0);
        f4 ua = ld4(Pi + ro1 + x1), ub = ld4(Pi + ro0 + x1);
        f4 uc = ld4(Pi + ro1 + x0), ud = ld4(Pi + ro0 + x0);
        f4 sv = sa - sb - sc + sd;
        f4 si = ua - ub - uc + ud;
        #pragma unroll
        for (int q = 0; q < 4; ++q) {
            float d  = sv[q] + si[q] + epsw[k];
            float wt = sv[q] * __builtin_amdgcn_rcpf(d);
            float dx = rx[q] - wt * dvx[q];
            float dy = ry[q] - wt * dvy[q];
            acc += dx * dx + dy * dy;
        }
    }

    // block reduction (f64, deterministic)
    double a = (double)acc;
    const int lane = threadIdx.x & 63, wid = threadIdx.x >> 6;
    #pragma unroll
    for (int off = 32; off > 0; off >>= 1) a += __shfl_down(a, off, 64);
    __shared__ double red[4];
    if (lane == 0) red[wid] = a;
    __syncthreads();
    if (threadIdx.x == 0)
        partials[bid] = red[0] + red[1] + red[2] + red[3];
}

// ---- kernel 5: final reduce ----------------------------------------------
__global__ __launch_bounds__(256) void k_reduce(const double* __restrict__ partials,
                                                int np, float* __restrict__ out) {
    __shared__ double red[256];
    double s = 0.0;
    for (int idx = threadIdx.x; idx < np; idx += 256) s += partials[idx];
    red[threadIdx.x] = s;
    __syncthreads();
    #pragma unroll
    for (int t = 128; t > 0; t >>= 1) {
        if (threadIdx.x < t) red[threadIdx.x] += red[threadIdx.x + t];
        __syncthreads();
    }
    if (threadIdx.x == 0)
        out[0] = (float)(red[0] / (double)((size_t)NIMG * H * W));
}

// ---- launch --------------------------------------------------------------

extern "C" void kernel_launch(void* const* d_in, const int* in_sizes, int n_in,
                              void* d_out, int out_size, void* d_ws, size_t ws_size,
                              hipStream_t stream) {
    const float* v   = (const float*)d_in[0];
    const float* i_  = (const float*)d_in[1];
    const float* img = (const float*)d_in[2];
    float* out = (float*)d_out;

    float* B         = (float*)d_ws;                               // 16 * 513*513 f32 = 16.8 MB
    float* bandsum   = B + (size_t)16 * SAT_PER;                   // 16 * 16 * 513 f32
    float* P         = bandsum + (size_t)16 * NBAND * SW;          // 16 * 576*576 f32 = 21.2 MB
    double* partials = (double*)(P + (size_t)16 * PP);             // 2048 f64

    k_rowscan<<<dim3(512 * NIMG * 2), dim3(512), 0, stream>>>(v, i_, B);
    k_bandsum<<<dim3(NBAND * NIMG * 2), dim3(576), 0, stream>>>(B, bandsum);
    k_bandapplyP<<<dim3(NBAND * NIMG * 2), dim3(576), 0, stream>>>(B, bandsum, P);
    k_main<<<dim3(2048), dim3(256), 0, stream>>>(v, i_, img, P, partials);
    k_reduce<<<dim3(1), dim3(256), 0, stream>>>(partials, 2048, out);
}

// Round 9
// 49.401 us; speedup vs baseline: 1.5390x; 1.1508x over previous
//
#include <hip/hip_runtime.h>

#define H 512
#define W 512
#define NIMG 8
#define NBAND 32
#define BROWS 16                  // rows per band (NBAND*BROWS == H)

#define PS 576                    // padded SAT stride (PADX=31 + 513 + 32)
#define PP (PS * PS)
#define PADY 32                   // P row p = SAT row y' + 32
#define PADX 31                   // P col c = SAT col x' + 31  (keeps f4 alignment)

#define TSTR 648                  // LDS tile stride (floats) >= phi(575)+4

typedef float f4 __attribute__((ext_vector_type(4), aligned(4)));
typedef float f2 __attribute__((ext_vector_type(2), aligned(4)));

__device__ __forceinline__ int phi(int c) { return c + 4 * (c >> 5); }  // bank spread

__device__ __forceinline__ f4 ld4(const float* p) {
    return *reinterpret_cast<const f4*>(p);
}

// zero-padded global load ('SAME' conv padding)
__device__ __forceinline__ float ldz(const float* __restrict__ p, int y, int x) {
    return ((unsigned)y < (unsigned)H && (unsigned)x < (unsigned)W) ? p[y * W + x] : 0.0f;
}

// load window [x0-1, x0+8] of row `row` (zero-padded), x0 = 8*lane
__device__ __forceinline__ void loadrow(const float* __restrict__ src, int row,
                                        int x0, int lane, float w[10]) {
    f4 a = {0.f, 0.f, 0.f, 0.f}, b = {0.f, 0.f, 0.f, 0.f};
    if ((unsigned)row < (unsigned)H) {
        const float* p = src + (size_t)row * W + x0;
        a = ld4(p);
        b = ld4(p + 4);
    }
    float left = __shfl_up(b[3], 1, 64);
    if (lane == 0) left = 0.f;
    float right = __shfl_down(a[0], 1, 64);
    if (lane == 63) right = 0.f;
    w[0] = left;
    w[1] = a[0]; w[2] = a[1]; w[3] = a[2]; w[4] = a[3];
    w[5] = b[0]; w[6] = b[1]; w[7] = b[2]; w[8] = b[3];
    w[9] = right;
}

// ---- kernel 1: energy + row prefix -> padded P rows + per-band col sums --
// 1-D grid 512: n = bid&7 (XCD pin), m, band b. Block: 512 thr, 8 waves.
__global__ __launch_bounds__(512) void k_rowband(const float* __restrict__ v,
                                                 const float* __restrict__ i_,
                                                 float* __restrict__ P,
                                                 float* __restrict__ bandsum) {
    const int bid = blockIdx.x;
    const int n = bid & 7;
    const int t = bid >> 3;
    const int m = t & 1;
    const int b = t >> 1;                      // 0..31
    const int map = n * 2 + m;
    const float* src = (m == 0 ? v : i_) + (size_t)n * (H * W);
    float* Pm = P + (size_t)map * PP;

    __shared__ float tile[BROWS][TSTR];        // 41.5 KB

    const int tid = threadIdx.x;
    const int lane = tid & 63, wv = tid >> 6;  // wv 0..7
    const int x0 = lane * 8;

    // band-0 blocks also zero P rows 0..32 (top pad + SAT row 0)
    if (b == 0) {
        const f4 z = {0.f, 0.f, 0.f, 0.f};
        for (int s = tid; s < 33 * (PS / 4); s += 512) {
            int j = s / (PS / 4), c4 = s - j * (PS / 4);
            *reinterpret_cast<f4*>(Pm + (size_t)j * PS + 4 * c4) = z;
        }
    }

    #pragma unroll
    for (int k = 0; k < 2; ++k) {
        const int j = k * 8 + wv;              // row within band, 0..15
        const int y = b * BROWS + j;           // image row
        float w0[10], w1[10], w2[10];
        loadrow(src, y - 1, x0, lane, w0);
        loadrow(src, y,     x0, lane, w1);
        loadrow(src, y + 1, x0, lane, w2);
        float e[8];
        #pragma unroll
        for (int q = 0; q < 8; ++q) {
            float gx = (w0[q + 2] - w0[q]) + 2.0f * (w1[q + 2] - w1[q]) + (w2[q + 2] - w2[q]);
            float gy = (w2[q] - w0[q]) + 2.0f * (w2[q + 1] - w0[q + 1]) + (w2[q + 2] - w0[q + 2]);
            e[q] = gx * gx + gy * gy;
        }
        #pragma unroll
        for (int q = 1; q < 8; ++q) e[q] += e[q - 1];   // in-lane prefix
        const float tot = e[7];
        float s = tot;                                   // wave scan of lane totals
        #pragma unroll
        for (int off = 1; off < 64; off <<= 1) {
            float t2 = __shfl_up(s, off, 64);
            if (lane >= off) s += t2;
        }
        const float excl = s - tot;
        const int pc = phi(32 + x0);           // contiguous for q=0..7 (within 32-block)
        #pragma unroll
        for (int q = 0; q < 8; ++q) tile[j][pc + q] = e[q] + excl;
    }
    __syncthreads();

    // pads in LDS: left cols 0..31 = 0 (SAT col <= 0); right cols 544..575 = col 543
    {
        const int j = tid >> 5, c = tid & 31;  // 16 rows x 32 cols = 512 threads
        tile[j][phi(c)] = 0.f;
        tile[j][phi(544 + c)] = tile[j][phi(543)];
    }
    __syncthreads();

    // per-band column sums (incl. pad cols) for the column-accumulate pass
    float* bs = bandsum + ((size_t)map * NBAND + b) * PS;
    for (int c = tid; c < PS; c += 512) {
        float s = 0.f;
        #pragma unroll
        for (int j = 0; j < BROWS; ++j) s += tile[j][phi(c)];
        bs[c] = s;
    }

    // coalesced padded row-prefix writeout: P rows 33+16b .. 48+16b
    for (int s4 = tid; s4 < BROWS * (PS / 4); s4 += 512) {
        int j = s4 / (PS / 4), c4 = s4 - j * (PS / 4);
        f4 val = *reinterpret_cast<const f4*>(&tile[j][phi(4 * c4)]);
        *reinterpret_cast<f4*>(Pm + (size_t)(PADY + 1 + b * BROWS + j) * PS + 4 * c4) = val;
    }
}

// ---- kernel 2: in-place column accumulate on P (band offsets inline) -----
__global__ __launch_bounds__(576) void k_colapply(float* __restrict__ P,
                                                  const float* __restrict__ bandsum) {
    const int bid = blockIdx.x;
    const int n = bid & 7;
    const int t = bid >> 3;
    const int m = t & 1;
    const int b = t >> 1;
    const int map = n * 2 + m;
    const int c = threadIdx.x;                 // 0..575
    const float* bs = bandsum + (size_t)map * NBAND * PS + c;
    float run = 0.f;
    for (int bb = 0; bb < b; ++bb) run += bs[(size_t)bb * PS];
    float* Pr = P + (size_t)map * PP + (size_t)(PADY + 1 + b * BROWS) * PS + c;
    #pragma unroll
    for (int j = 0; j < BROWS; ++j) {
        run += Pr[(size_t)j * PS];
        Pr[(size_t)j * PS] = run;
    }
    if (b == NBAND - 1) {                      // bottom pad rows 545..575 = SAT row 512
        float* Pp = P + (size_t)map * PP + (size_t)(PADY + 1 + H) * PS + c;
        #pragma unroll
        for (int j = 0; j < PS - (PADY + 1 + H); ++j)
            Pp[(size_t)j * PS] = run;
    }
}

// ---- sobel for 4 consecutive pixels (vectorized fast path) ---------------
__device__ __forceinline__ void sobel4(const float* __restrict__ p, int y, int x4,
                                       bool fast, float gx[4], float gy[4]) {
    float r0[6], r1[6], r2[6];
    if (fast) {
        const float* a = p + (size_t)(y - 1) * W + (x4 - 1);
        f4 A = ld4(a);             f2 Ab = *reinterpret_cast<const f2*>(a + 4);
        f4 Bv = ld4(a + W);        f2 Bb = *reinterpret_cast<const f2*>(a + W + 4);
        f4 Cv = ld4(a + 2 * W);    f2 Cb = *reinterpret_cast<const f2*>(a + 2 * W + 4);
        r0[0]=A[0];  r0[1]=A[1];  r0[2]=A[2];  r0[3]=A[3];  r0[4]=Ab[0]; r0[5]=Ab[1];
        r1[0]=Bv[0]; r1[1]=Bv[1]; r1[2]=Bv[2]; r1[3]=Bv[3]; r1[4]=Bb[0]; r1[5]=Bb[1];
        r2[0]=Cv[0]; r2[1]=Cv[1]; r2[2]=Cv[2]; r2[3]=Cv[3]; r2[4]=Cb[0]; r2[5]=Cb[1];
    } else {
        #pragma unroll
        for (int q = 0; q < 6; ++q) {
            r0[q] = ldz(p, y - 1, x4 - 1 + q);
            r1[q] = ldz(p, y,     x4 - 1 + q);
            r2[q] = ldz(p, y + 1, x4 - 1 + q);
        }
    }
    #pragma unroll
    for (int q = 0; q < 4; ++q) {
        gx[q] = (r0[q + 2] - r0[q]) + 2.0f * (r1[q + 2] - r1[q]) + (r2[q + 2] - r2[q]);
        gy[q] = (r2[q] - r0[q]) + 2.0f * (r2[q + 1] - r0[q + 1]) + (r2[q + 2] - r0[q + 2]);
    }
}

// ---- kernel 3: fused sobel + clamp-free f4 SAT gather + residual ---------
__global__ __launch_bounds__(256) void k_main(const float* __restrict__ v,
                                              const float* __restrict__ i_,
                                              const float* __restrict__ img,
                                              const float* __restrict__ P,
                                              double* __restrict__ partials) {
    const int bid = blockIdx.x;
    const int n = bid & 7;                     // image -> XCD pin
    const int t = bid >> 3;                    // 0..255
    const int tx = t & 3, ty = t >> 2;         // tile: 128 wide x 8 rows
    const int col = threadIdx.x & 31, row = threadIdx.x >> 5;
    const int x4 = tx * 128 + col * 4;
    const int y  = ty * 8 + row;

    const float* pv = v   + (size_t)n * (H * W);
    const float* pi = i_  + (size_t)n * (H * W);
    const float* pf = img + (size_t)n * (H * W);
    const float* Pv = P + (size_t)(n * 2 + 0) * PP;
    const float* Pi = P + (size_t)(n * 2 + 1) * PP;

    float gvx[4], gvy[4], gix[4], giy[4], gfx[4], gfy[4];
    const bool fast = (y >= 1 && y <= H - 2 && x4 >= 4 && x4 <= W - 8);
    sobel4(pv, y, x4, fast, gvx, gvy);
    sobel4(pi, y, x4, fast, gix, giy);
    sobel4(pf, y, x4, fast, gfx, gfy);

    float dvx[4], dvy[4], rx[4], ry[4];
    #pragma unroll
    for (int q = 0; q < 4; ++q) {
        dvx[q] = gvx[q] - gix[q];
        dvy[q] = gvy[q] - giy[q];
        rx[q]  = gfx[q] - gix[q];
        ry[q]  = gfy[q] - giy[q];
    }

    const int   radii[5] = {1, 3, 7, 15, 30};
    // wt = sv / (sv + si + eps*w^2)  (identical algebra to reference)
    const float epsw[5]  = {9e-8f, 4.9e-7f, 2.25e-6f, 9.61e-6f, 3.721e-5f};

    float acc = 0.0f;
    #pragma unroll
    for (int k = 0; k < 5; ++k) {
        const int r = radii[k];
        const size_t ro0 = (size_t)(y - r + PADY) * PS;
        const size_t ro1 = (size_t)(y + r + 1 + PADY) * PS;
        const int x0 = x4 - r + PADX;
        const int x1 = x4 + r + 1 + PADX;
        f4 sa = ld4(Pv + ro1 + x1), sb = ld4(Pv + ro0 + x1);
        f4 sc = ld4(Pv + ro1 + x0), sd = ld4(Pv + ro0 + x0);
        f4 ua = ld4(Pi + ro1 + x1), ub = ld4(Pi + ro0 + x1);
        f4 uc = ld4(Pi + ro1 + x0), ud = ld4(Pi + ro0 + x0);
        f4 sv = sa - sb - sc + sd;
        f4 si = ua - ub - uc + ud;
        #pragma unroll
        for (int q = 0; q < 4; ++q) {
            float d  = sv[q] + si[q] + epsw[k];
            float wt = sv[q] * __builtin_amdgcn_rcpf(d);
            float dx = rx[q] - wt * dvx[q];
            float dy = ry[q] - wt * dvy[q];
            acc += dx * dx + dy * dy;
        }
    }

    // block reduction (f64, deterministic)
    double a = (double)acc;
    const int lane = threadIdx.x & 63, wid = threadIdx.x >> 6;
    #pragma unroll
    for (int off = 32; off > 0; off >>= 1) a += __shfl_down(a, off, 64);
    __shared__ double red[4];
    if (lane == 0) red[wid] = a;
    __syncthreads();
    if (threadIdx.x == 0)
        partials[bid] = red[0] + red[1] + red[2] + red[3];
}

// ---- kernel 4: final reduce ----------------------------------------------
__global__ __launch_bounds__(256) void k_reduce(const double* __restrict__ partials,
                                                int np, float* __restrict__ out) {
    __shared__ double red[256];
    double s = 0.0;
    for (int idx = threadIdx.x; idx < np; idx += 256) s += partials[idx];
    red[threadIdx.x] = s;
    __syncthreads();
    #pragma unroll
    for (int t = 128; t > 0; t >>= 1) {
        if (threadIdx.x < t) red[threadIdx.x] += red[threadIdx.x + t];
        __syncthreads();
    }
    if (threadIdx.x == 0)
        out[0] = (float)(red[0] / (double)((size_t)NIMG * H * W));
}

// ---- launch --------------------------------------------------------------

extern "C" void kernel_launch(void* const* d_in, const int* in_sizes, int n_in,
                              void* d_out, int out_size, void* d_ws, size_t ws_size,
                              hipStream_t stream) {
    const float* v   = (const float*)d_in[0];
    const float* i_  = (const float*)d_in[1];
    const float* img = (const float*)d_in[2];
    float* out = (float*)d_out;

    float* P         = (float*)d_ws;                               // 16 * 576*576 f32 = 21.2 MB
    float* bandsum   = P + (size_t)16 * PP;                        // 16 * 32 * 576 f32 = 1.2 MB
    double* partials = (double*)(bandsum + (size_t)16 * NBAND * PS);  // 2048 f64

    k_rowband<<<dim3(NBAND * NIMG * 2), dim3(512), 0, stream>>>(v, i_, P, bandsum);
    k_colapply<<<dim3(NBAND * NIMG * 2), dim3(576), 0, stream>>>(P, bandsum);
    k_main<<<dim3(2048), dim3(256), 0, stream>>>(v, i_, img, P, partials);
    k_reduce<<<dim3(1), dim3(256), 0, stream>>>(partials, 2048, out);
}